// Round 6
// baseline (580.892 us; speedup 1.0000x reference)
//
#include <hip/hip_runtime.h>

typedef unsigned short u16;
typedef __bf16 bf16x8 __attribute__((ext_vector_type(8)));
typedef float f32x4v __attribute__((ext_vector_type(4)));
typedef u16 u16x8 __attribute__((ext_vector_type(8)));

__device__ __forceinline__ u16 f2bf(float f) {
  union { float f; unsigned u; } v; v.f = f;
  unsigned r = v.u + 0x7fffu + ((v.u >> 16) & 1u);  // round-to-nearest-even
  return (u16)(r >> 16);
}
__device__ __forceinline__ float bf2f(u16 h) {
  union { unsigned u; float f; } v; v.u = ((unsigned)h) << 16;
  return v.f;
}

#define G2L16(g, l)                                                            \
  __builtin_amdgcn_global_load_lds((__attribute__((address_space(1))) void*)(g), \
                                   (__attribute__((address_space(3))) void*)(l), 16, 0, 0)

// ---------- fused prep: W-transposes (bids 0..4095) + PQ table (4096..4351) --
__global__ __launch_bounds__(256) void k_prep(const float* __restrict__ W1,
                                              u16* __restrict__ W1T,
                                              const float* __restrict__ W2,
                                              u16* __restrict__ W2gT,
                                              const float* __restrict__ g1,
                                              const float* __restrict__ bt1,
                                              float* __restrict__ w2ps,
                                              float* __restrict__ w2pc,
                                              const float* __restrict__ x1,
                                              const float* __restrict__ We,
                                              float* __restrict__ pq) {
  __shared__ float lds[4224];   // transpose: 64x65; pq: 32x33 + 32x68
  int bid = blockIdx.x;
  const int t = threadIdx.x;
  if (bid < 4096) {
    float (*tile)[65] = (float(*)[65])lds;
    const float* in;
    u16* out;
    int R, C, bx, by, fold;
    if (bid < 2048) {            // W1: 32 row-tiles x 64 col-tiles
      in = W1; out = W1T; R = 2048; C = 4096; fold = 0;
      bx = bid & 63; by = bid >> 6;
    } else {                     // W2: 64 row-tiles x 32 col-tiles
      bid -= 2048;
      in = W2; out = W2gT; R = 4096; C = 2048; fold = 1;
      bx = bid & 31; by = bid >> 5;
    }
    const int c0 = bx * 64, r0 = by * 64;
    const int tc = (t & 15) * 4, tr = t >> 4;
#pragma unroll
    for (int i = 0; i < 4; ++i) {
      int r = tr + i * 16;
      f32x4v v = *(const f32x4v*)(in + (size_t)(r0 + r) * C + c0 + tc);
      tile[r][tc] = v[0]; tile[r][tc + 1] = v[1];
      tile[r][tc + 2] = v[2]; tile[r][tc + 3] = v[3];
    }
    __syncthreads();
    const int oc = t >> 2;        // output row (= input col) 0..63
    const int rb = (t & 3) * 16;  // 16 input rows each
    float gv[16];
#pragma unroll
    for (int i = 0; i < 16; ++i) gv[i] = fold ? g1[r0 + rb + i] : 1.f;
    u16x8 o0, o1;
#pragma unroll
    for (int i = 0; i < 8; ++i) o0[i] = f2bf(tile[rb + i][oc] * gv[i]);
#pragma unroll
    for (int i = 0; i < 8; ++i) o1[i] = f2bf(tile[rb + 8 + i][oc] * gv[8 + i]);
    *(u16x8*)(out + (size_t)(c0 + oc) * R + r0 + rb) = o0;
    *(u16x8*)(out + (size_t)(c0 + oc) * R + r0 + rb + 8) = o1;
    if (fold) {
      float ps = 0.f, pc = 0.f;
#pragma unroll
      for (int i = 0; i < 16; ++i) {
        float w = tile[rb + i][oc];
        ps += gv[i] * w;
        pc += bt1[r0 + rb + i] * w;
      }
      ps += __shfl_down(ps, 2, 4); ps += __shfl_down(ps, 1, 4);
      pc += __shfl_down(pc, 2, 4); pc += __shfl_down(pc, 1, 4);
      if ((t & 3) == 0) {
        w2ps[(size_t)by * 2048 + c0 + oc] = ps;
        w2pc[(size_t)by * 2048 + c0 + oc] = pc;
      }
    }
  } else {
    // ---- PQ path: full-K accumulation ----
    const int pqb = bid - 4096;          // 0..255
    const int n0 = (pqb & 15) * 64;
    const int ep = (pqb >> 4) & 7;       // e*2+p
    const int e = ep >> 1, p = ep & 1;
    const int chalf = pqb >> 7;
    float (*As)[33] = (float(*)[33])lds;
    float (*Bs)[68] = (float(*)[68])(lds + 32 * 33);
    const int tx = t & 15, ty = t >> 4;
    float acc[2][4] = {};
    const float* wbase = We + (size_t)e * 2048 * 1024 + (size_t)p * 1024 * 1024;
    for (int k0 = 0; k0 < 1024; k0 += 32) {
#pragma unroll
      for (int i = 0; i < 4; ++i) {
        int ix = t + i * 256;
        As[ix >> 5][ix & 31] =
            x1[(size_t)(chalf * 32 + (ix >> 5)) * 1024 + k0 + (ix & 31)];
      }
#pragma unroll
      for (int i = 0; i < 8; ++i) {
        int ix = t + i * 256;
        Bs[ix >> 6][ix & 63] = wbase[(size_t)(k0 + (ix >> 6)) * 1024 + n0 + (ix & 63)];
      }
      __syncthreads();
#pragma unroll
      for (int kk = 0; kk < 32; ++kk) {
        float av[2];
#pragma unroll
        for (int i = 0; i < 2; ++i) av[i] = As[ty * 2 + i][kk];
        f32x4v bv = *(const f32x4v*)&Bs[kk][tx * 4];
#pragma unroll
        for (int i = 0; i < 2; ++i)
#pragma unroll
          for (int j = 0; j < 4; ++j) acc[i][j] += av[i] * bv[j];
      }
      __syncthreads();
    }
#pragma unroll
    for (int i = 0; i < 2; ++i) {
      float* dst = pq + ((size_t)ep * 64 + chalf * 32 + ty * 2 + i) * 1024 + n0 + tx * 4;
#pragma unroll
      for (int j = 0; j < 4; ++j) dst[j] = acc[i][j];
    }
  }
}

// -------- build Y (bids 0..1023) + reduction extras (1024..1035) ------------
// extras: s1/c1b from w2ps/w2pc (8 blocks), gw3+scal (1 block), zero
// stats_sum 64KB (1 block), zero rowacc 128KB (2 blocks).
__global__ __launch_bounds__(256) void k_build_y(const float* __restrict__ pq,
                                                 const float* __restrict__ x2,
                                                 const float* __restrict__ be,
                                                 const int* __restrict__ cp,
                                                 const int* __restrict__ vis,
                                                 u16* __restrict__ Y,
                                                 const float* __restrict__ w2ps,
                                                 const float* __restrict__ w2pc,
                                                 const float* __restrict__ b2,
                                                 float* __restrict__ s1,
                                                 float* __restrict__ c1b,
                                                 const float* __restrict__ g2,
                                                 const float* __restrict__ bt2,
                                                 const float* __restrict__ W3,
                                                 float* __restrict__ gw3,
                                                 float* __restrict__ scal,
                                                 float* __restrict__ ssum,
                                                 float* __restrict__ rowacc) {
  __shared__ float red[8];
  const int t = threadIdx.x;
  const int bidx = blockIdx.x;
  if (bidx < 1024) {
    for (int rr = 0; rr < 8; ++rr) {
      const int b = bidx * 8 + rr;
      const int e = vis[b];
      u16x8 o;
      if (t < 128) {
        const int c0 = cp[2 * b], c1 = cp[2 * b + 1];
        const size_t po = ((size_t)(e * 2) * 64 + c0) * 1024 + t * 8;
        const size_t qo = ((size_t)(e * 2 + 1) * 64 + c1) * 1024 + t * 8;
        const float* B = be + e * 1024 + t * 8;
#pragma unroll
        for (int i = 0; i < 8; ++i) {
          float v = pq[po + i] + pq[qo + i] + B[i];
          o[i] = f2bf(v > 0.f ? v : 0.f);
        }
        *(u16x8*)(Y + (size_t)b * 2048 + t * 8) = o;
      } else {
        const float* X = x2 + (size_t)b * 1024 + (size_t)(t - 128) * 8;
#pragma unroll
        for (int i = 0; i < 8; ++i) o[i] = f2bf(X[i]);
        *(u16x8*)(Y + (size_t)b * 2048 + 1024 + (size_t)(t - 128) * 8) = o;
      }
    }
  } else {
    const int r = bidx - 1024;
    if (r < 8) {
      const int nn = r * 256 + t;
      float s = 0.f, c = 0.f;
      for (int kb = 0; kb < 64; ++kb) {
        s += w2ps[(size_t)kb * 2048 + nn];
        c += w2pc[(size_t)kb * 2048 + nn];
      }
      s1[nn] = s;
      c1b[nn] = c + b2[nn];
    } else if (r == 8) {
      float sg = 0.f, cb = 0.f;
      for (int i = 0; i < 8; ++i) {
        int c = i * 256 + t;
        float w3 = W3[c];
        float gv = g2[c] * w3;
        gw3[c] = gv;
        sg += gv;
        cb += bt2[c] * w3;
      }
#pragma unroll
      for (int off = 32; off > 0; off >>= 1) {
        sg += __shfl_down(sg, off, 64);
        cb += __shfl_down(cb, off, 64);
      }
      const int lane = t & 63, wv = t >> 6;
      if (lane == 0) { red[wv] = sg; red[4 + wv] = cb; }
      __syncthreads();
      if (t == 0) {
        scal[0] = red[0] + red[1] + red[2] + red[3];
        scal[1] = red[4] + red[5] + red[6] + red[7];
      }
    } else if (r == 9) {
      // zero ssum: 16384 floats
      float4* p = (float4*)ssum;
#pragma unroll 4
      for (int i = t; i < 4096; i += 256) p[i] = make_float4(0.f, 0.f, 0.f, 0.f);
    } else {
      // r = 10,11: zero rowacc: 32768 floats
      float4* p = (float4*)rowacc + (r - 10) * 4096;
#pragma unroll 4
      for (int i = t; i < 4096; i += 256) p[i] = make_float4(0.f, 0.f, 0.f, 0.f);
    }
  }
}

// ============================================================================
// bf16 MFMA GEMM — 256x256 tile, BK=64, 8 waves (2Mx4N), 16x16x32 MFMA,
// XOR-chunk swizzle both-sides, XCD swizzle, setprio. Round-5 K-loop
// (intra-tile read pipelining, counted lgkm, 1 barrier/phase) UNCHANGED.
// MODE 0: C=relu(acc+bias) store; row (sum,sumsq) -> atomicAdd ssum[row].
// MODE 1: LN1 applied inline from ssum; (S,SS,D) -> atomicAdd rowacc[row].
// ============================================================================
#define BARRIER __builtin_amdgcn_s_barrier()
#define WLG(n) asm volatile("s_waitcnt lgkmcnt(" #n ")" ::: "memory")
#define WVM(n) asm volatile("s_waitcnt vmcnt(" #n ")" ::: "memory")

template <int MODE>
__global__ __launch_bounds__(512, 2) void k_gemm(const u16* __restrict__ A,
                                                 const u16* __restrict__ BT,
                                                 const float* __restrict__ bias,
                                                 const float2* __restrict__ stats,
                                                 const float* __restrict__ s1,
                                                 const float* __restrict__ c1b,
                                                 const float* __restrict__ gw3,
                                                 float* __restrict__ ssum,
                                                 float* __restrict__ rowacc,
                                                 u16* __restrict__ C,
                                                 int M, int N, int K) {
  // [buf(2)][ab(2)][half(2)][128 rows][64 k] bf16 = 128 KiB
  __shared__ u16 smem[65536];
  const int tid = threadIdx.x;
  const int lane = tid & 63;
  const int wave = tid >> 6;
  const int wm = wave >> 2;   // 0..1 -> 128 output rows
  const int wn = wave & 3;    // 0..3 -> 64 output cols

  // Bijective XCD swizzle.
  const int nx = gridDim.x, ny = gridDim.y;
  const int bid = blockIdx.y * nx + blockIdx.x;
  const int stripe = ny >> 3;                  // ny % 8 == 0 here
  const int xcd = bid & 7;
  const int loc = bid >> 3;
  const int by = xcd * stripe + (loc % stripe);
  const int bx = loc / stripe;
  const int tileM = by * 256;
  const int tileN = bx * 256;

  f32x4v acc[8][4];
#pragma unroll
  for (int i = 0; i < 8; ++i)
#pragma unroll
    for (int j = 0; j < 4; ++j) acc[i][j] = (f32x4v){0.f, 0.f, 0.f, 0.f};

  const int srow = tid >> 3;
  const int slc = ((tid & 7) ^ (srow & 7)) * 8;
  const u16* aG = A + (size_t)(tileM + srow) * K + slc;
  const u16* bG = BT + (size_t)(tileN + srow) * K + slc;

#define STAGE(ab, h, buf, kt)                                                  \
  do {                                                                         \
    u16* dst_ = smem + (buf) * 32768 + (ab) * 16384 + (h) * 8192 + tid * 8;    \
    const u16* g_ = ((ab) ? bG : aG) + (size_t)(h) * 128 * K + (size_t)(kt) * 64; \
    G2L16(g_, dst_);                                                           \
    G2L16(g_ + (size_t)64 * K, dst_ + 4096);                                   \
  } while (0)

  const int kp0 = (((lane >> 4) ^ (lane & 7)) * 8);
  const int kp1 = kp0 ^ 32;
  const int awoff = wm * 8192 + (lane & 15) * 64;
  const int bwoff = (wn >> 1) * 8192 + ((wn & 1) * 64 + (lane & 15)) * 64;

  bf16x8 af[2][4], ag[2][4], bfr[2][4];

#define RD_AF(buf)                                                             \
  do {                                                                         \
    const u16* ap_ = smem + (buf) * 32768 + awoff;                             \
    _Pragma("unroll") for (int q = 0; q < 4; ++q) {                            \
      af[0][q] = *(const bf16x8*)(ap_ + q * 1024 + kp0);                       \
      af[1][q] = *(const bf16x8*)(ap_ + q * 1024 + kp1);                       \
    }                                                                          \
  } while (0)

#define RD_AG(buf)                                                             \
  do {                                                                         \
    const u16* ap_ = smem + (buf) * 32768 + awoff + 4096;                      \
    _Pragma("unroll") for (int q = 0; q < 4; ++q) {                            \
      ag[0][q] = *(const bf16x8*)(ap_ + q * 1024 + kp0);                       \
      ag[1][q] = *(const bf16x8*)(ap_ + q * 1024 + kp1);                       \
    }                                                                          \
  } while (0)

#define RD_BB(buf)                                                             \
  do {                                                                         \
    const u16* bp_ = smem + (buf) * 32768 + 16384 + bwoff;                     \
    _Pragma("unroll") for (int j = 0; j < 4; ++j) {                            \
      bfr[0][j] = *(const bf16x8*)(bp_ + j * 1024 + kp0);                      \
      bfr[1][j] = *(const bf16x8*)(bp_ + j * 1024 + kp1);                      \
    }                                                                          \
  } while (0)

#define QUAD(AF, mh, nh)                                                       \
  do {                                                                         \
    __builtin_amdgcn_s_setprio(1);                                             \
    _Pragma("unroll") for (int kh = 0; kh < 2; ++kh)                           \
    _Pragma("unroll") for (int q = 0; q < 4; ++q)                              \
    _Pragma("unroll") for (int p = 0; p < 2; ++p)                              \
      acc[(mh) * 4 + q][(nh) * 2 + p] = __builtin_amdgcn_mfma_f32_16x16x32_bf16( \
          AF[kh][q], bfr[(kh)][(nh) * 2 + p], acc[(mh) * 4 + q][(nh) * 2 + p], 0, 0, 0); \
    __builtin_amdgcn_s_setprio(0);                                             \
  } while (0)

  const int nkt = K >> 6;       // 64-wide K-tiles
  const int niter = nkt >> 1;   // 2 K-tiles per iteration

  STAGE(1, 0, 0, 0);  // B0 T0
  STAGE(1, 1, 0, 0);  // B1 T0
  STAGE(0, 0, 0, 0);  // A0 T0
  STAGE(0, 1, 0, 0);  // A1 T0
  STAGE(1, 0, 1, 1);  // B0 T1
  STAGE(1, 1, 1, 1);  // B1 T1
  WVM(4);

  for (int it = 0; it < niter; ++it) {
    const int t1 = 2 * it + 1;
    int t2 = 2 * it + 2; if (t2 >= nkt) t2 = nkt - 1;
    int t3 = 2 * it + 3; if (t3 >= nkt) t3 = nkt - 1;
    // ===== tile T0 @ s0 =====
    BARRIER;
    RD_AF(0); RD_BB(0);
    STAGE(0, 0, 1, t1);
    WLG(4);
    QUAD(af, 0, 0);
    BARRIER;
    RD_AG(0);
    STAGE(0, 1, 1, t1);
    WLG(8);
    QUAD(af, 0, 1);
    BARRIER;
    STAGE(1, 0, 0, t2);
    WLG(0);
    QUAD(ag, 1, 0);
    BARRIER;
    STAGE(1, 1, 0, t2);
    QUAD(ag, 1, 1);
    WVM(4);
    // ===== tile T1 @ s1 =====
    BARRIER;
    RD_AF(1); RD_BB(1);
    STAGE(0, 0, 0, t2);
    WLG(4);
    QUAD(af, 0, 0);
    BARRIER;
    RD_AG(1);
    STAGE(0, 1, 0, t2);
    WLG(8);
    QUAD(af, 0, 1);
    BARRIER;
    STAGE(1, 0, 1, t3);
    WLG(0);
    QUAD(ag, 1, 0);
    BARRIER;
    STAGE(1, 1, 1, t3);
    QUAD(ag, 1, 1);
    WVM(4);
  }

  // ---- epilogue: C/D layout col = lane&15, row = (lane>>4)*4 + reg
  const int crow = tileM + wm * 128 + (lane >> 4) * 4;
  const int ccol = tileN + wn * 64 + (lane & 15);
  float cv0[4], cv1[4], cg[4];
#pragma unroll
  for (int ni = 0; ni < 4; ++ni) {
    const int c = ccol + ni * 16;
    if (MODE == 0) {
      cv0[ni] = bias[c];
    } else {
      cv0[ni] = s1[c];
      cv1[ni] = c1b[c];
      cg[ni] = gw3[c];
    }
  }
#pragma unroll
  for (int mi = 0; mi < 8; ++mi) {
#pragma unroll
    for (int r = 0; r < 4; ++r) {
      const int row = crow + mi * 16 + r;
      if (MODE == 0) {
        float s_ = 0.f, ss_ = 0.f;
#pragma unroll
        for (int ni = 0; ni < 4; ++ni) {
          float v = acc[mi][ni][r] + cv0[ni];
          v = v > 0.f ? v : 0.f;
          s_ += v; ss_ += v * v;
          C[(size_t)row * N + ccol + ni * 16] = f2bf(v);
        }
#pragma unroll
        for (int off = 8; off >= 1; off >>= 1) {
          s_ += __shfl_xor(s_, off, 16);
          ss_ += __shfl_xor(ss_, off, 16);
        }
        if ((lane & 15) == 0) {
          atomicAdd(ssum + (size_t)row * 2, s_);
          atomicAdd(ssum + (size_t)row * 2 + 1, ss_);
        }
      } else {
        float2 sv = stats[row];   // raw (S, SS) sums from MODE0 atomics
        const float m = sv.x * (1.f / 4096.f);
        const float rs = rsqrtf(sv.y * (1.f / 4096.f) - m * m + 1e-5f);
        float s_ = 0.f, ss_ = 0.f, d_ = 0.f;
#pragma unroll
        for (int ni = 0; ni < 4; ++ni) {
          float v = rs * acc[mi][ni][r] - rs * m * cv0[ni] + cv1[ni];
          v = v > 0.f ? v : 0.f;
          s_ += v; ss_ += v * v; d_ += v * cg[ni];
        }
#pragma unroll
        for (int off = 8; off >= 1; off >>= 1) {
          s_ += __shfl_xor(s_, off, 16);
          ss_ += __shfl_xor(ss_, off, 16);
          d_ += __shfl_xor(d_, off, 16);
        }
        if ((lane & 15) == 0) {
          atomicAdd(rowacc + (size_t)row * 4, s_);
          atomicAdd(rowacc + (size_t)row * 4 + 1, ss_);
          atomicAdd(rowacc + (size_t)row * 4 + 2, d_);
        }
      }
    }
  }
}

// ------- final: out[row] = sigmoid(rs*D - rs*m*SG + CB + b3) ----------------
__global__ __launch_bounds__(256) void k_final(const float4* __restrict__ rowacc,
                                               const float* __restrict__ scal,
                                               const float* __restrict__ b3,
                                               float* __restrict__ out) {
  const int row = blockIdx.x * 256 + threadIdx.x;
  float4 a = rowacc[row];
  float m = a.x * (1.f / 2048.f);
  float rs = rsqrtf(a.y * (1.f / 2048.f) - m * m + 1e-5f);
  float logit = rs * a.z - rs * m * scal[0] + scal[1] + b3[0];
  out[row] = 1.f / (1.f + expf(-logit));
}

extern "C" void kernel_launch(void* const* d_in, const int* in_sizes, int n_in,
                              void* d_out, int out_size, void* d_ws, size_t ws_size,
                              hipStream_t stream) {
  const float* x1 = (const float*)d_in[0];
  const float* x2 = (const float*)d_in[1];
  const float* We = (const float*)d_in[2];
  const float* be = (const float*)d_in[3];
  const float* W1 = (const float*)d_in[4];
  const float* b1 = (const float*)d_in[5];
  const float* g1 = (const float*)d_in[6];
  const float* bt1 = (const float*)d_in[7];
  const float* W2 = (const float*)d_in[8];
  const float* b2 = (const float*)d_in[9];
  const float* g2 = (const float*)d_in[10];
  const float* bt2 = (const float*)d_in[11];
  const float* W3 = (const float*)d_in[12];
  const float* b3 = (const float*)d_in[13];
  const int* cp = (const int*)d_in[14];
  const int* vis = (const int*)d_in[15];
  float* out = (float*)d_out;

  char* ws = (char*)d_ws;
  u16* W1T  = (u16*)(ws);                  // 4096x2048 bf16 = 16 MiB
  u16* W2gT = (u16*)(ws + 16777216);       // 2048x4096 bf16 = 16 MiB
  u16* Y    = (u16*)(ws + 33554432);       // 8192x2048 bf16 = 32 MiB
  u16* H1   = (u16*)(ws + 67108864);       // 8192x4096 bf16 = 64 MiB
  float* PQ = (float*)(ws + 134217728);    // 8x64x1024 f32 = 2 MiB
  float* ssum   = (float*)(ws + 138412032);   // 8192 float2 = 64 KiB
  float* rowacc = (float*)(ws + 138477568);   // 8192 float4 = 128 KiB
  float* s1   = (float*)(ws + 138608640);     // 8 KiB
  float* c1b  = (float*)(ws + 138616832);     // 8 KiB
  float* w2ps = (float*)(ws + 138625024);     // 64x2048 f32 = 512 KiB
  float* w2pc = (float*)(ws + 139149312);     // 512 KiB
  float* gw3  = (float*)(ws + 139673600);     // 8 KiB
  float* scal = (float*)(ws + 139681792);     // 2 f32

  k_prep<<<4352, 256, 0, stream>>>(W1, W1T, W2, W2gT, g1, bt1, w2ps, w2pc,
                                   x1, We, PQ);
  k_build_y<<<1036, 256, 0, stream>>>(PQ, x2, be, cp, vis, Y,
                                      w2ps, w2pc, b2, s1, c1b,
                                      g2, bt2, W3, gw3, scal, ssum, rowacc);
  k_gemm<0><<<dim3(16, 32), 512, 0, stream>>>(
      Y, W1T, b1, nullptr, nullptr, nullptr, nullptr, ssum, nullptr, H1,
      8192, 4096, 2048);
  k_gemm<1><<<dim3(8, 32), 512, 0, stream>>>(
      H1, W2gT, nullptr, (const float2*)ssum, s1, c1b, gw3, nullptr, rowacc,
      nullptr, 8192, 2048, 4096);
  k_final<<<32, 256, 0, stream>>>((const float4*)rowacc, scal, b3, out);
}

// Round 7
// 474.315 us; speedup vs baseline: 1.2247x; 1.2247x over previous
//
#include <hip/hip_runtime.h>

typedef unsigned short u16;
typedef __bf16 bf16x8 __attribute__((ext_vector_type(8)));
typedef float f32x4v __attribute__((ext_vector_type(4)));
typedef u16 u16x8 __attribute__((ext_vector_type(8)));

__device__ __forceinline__ u16 f2bf(float f) {
  union { float f; unsigned u; } v; v.f = f;
  unsigned r = v.u + 0x7fffu + ((v.u >> 16) & 1u);  // round-to-nearest-even
  return (u16)(r >> 16);
}

#define G2L16(g, l)                                                            \
  __builtin_amdgcn_global_load_lds((__attribute__((address_space(1))) void*)(g), \
                                   (__attribute__((address_space(3))) void*)(l), 16, 0, 0)

// ---------- fused prep: W-transposes (bids 0..4095) + PQ table (4096..4351) --
__global__ __launch_bounds__(256) void k_prep(const float* __restrict__ W1,
                                              u16* __restrict__ W1T,
                                              const float* __restrict__ W2,
                                              u16* __restrict__ W2gT,
                                              const float* __restrict__ g1,
                                              const float* __restrict__ bt1,
                                              float* __restrict__ w2ps,
                                              float* __restrict__ w2pc,
                                              const float* __restrict__ x1,
                                              const float* __restrict__ We,
                                              float* __restrict__ pq) {
  __shared__ float lds[4224];   // transpose: 64x65; pq: 32x33 + 32x68
  int bid = blockIdx.x;
  const int t = threadIdx.x;
  if (bid < 4096) {
    float (*tile)[65] = (float(*)[65])lds;
    const float* in;
    u16* out;
    int R, C, bx, by, fold;
    if (bid < 2048) {            // W1: 32 row-tiles x 64 col-tiles
      in = W1; out = W1T; R = 2048; C = 4096; fold = 0;
      bx = bid & 63; by = bid >> 6;
    } else {                     // W2: 64 row-tiles x 32 col-tiles
      bid -= 2048;
      in = W2; out = W2gT; R = 4096; C = 2048; fold = 1;
      bx = bid & 31; by = bid >> 5;
    }
    const int c0 = bx * 64, r0 = by * 64;
    const int tc = (t & 15) * 4, tr = t >> 4;
#pragma unroll
    for (int i = 0; i < 4; ++i) {
      int r = tr + i * 16;
      f32x4v v = *(const f32x4v*)(in + (size_t)(r0 + r) * C + c0 + tc);
      tile[r][tc] = v[0]; tile[r][tc + 1] = v[1];
      tile[r][tc + 2] = v[2]; tile[r][tc + 3] = v[3];
    }
    __syncthreads();
    const int oc = t >> 2;        // output row (= input col) 0..63
    const int rb = (t & 3) * 16;  // 16 input rows each
    float gv[16];
#pragma unroll
    for (int i = 0; i < 16; ++i) gv[i] = fold ? g1[r0 + rb + i] : 1.f;
    u16x8 o0, o1;
#pragma unroll
    for (int i = 0; i < 8; ++i) o0[i] = f2bf(tile[rb + i][oc] * gv[i]);
#pragma unroll
    for (int i = 0; i < 8; ++i) o1[i] = f2bf(tile[rb + 8 + i][oc] * gv[8 + i]);
    *(u16x8*)(out + (size_t)(c0 + oc) * R + r0 + rb) = o0;
    *(u16x8*)(out + (size_t)(c0 + oc) * R + r0 + rb + 8) = o1;
    if (fold) {
      float ps = 0.f, pc = 0.f;
#pragma unroll
      for (int i = 0; i < 16; ++i) {
        float w = tile[rb + i][oc];
        ps += gv[i] * w;
        pc += bt1[r0 + rb + i] * w;
      }
      ps += __shfl_down(ps, 2, 4); ps += __shfl_down(ps, 1, 4);
      pc += __shfl_down(pc, 2, 4); pc += __shfl_down(pc, 1, 4);
      if ((t & 3) == 0) {
        w2ps[(size_t)by * 2048 + c0 + oc] = ps;
        w2pc[(size_t)by * 2048 + c0 + oc] = pc;
      }
    }
  } else {
    // ---- PQ path: full-K accumulation ----
    const int pqb = bid - 4096;          // 0..255
    const int n0 = (pqb & 15) * 64;
    const int ep = (pqb >> 4) & 7;       // e*2+p
    const int e = ep >> 1, p = ep & 1;
    const int chalf = pqb >> 7;
    float (*As)[33] = (float(*)[33])lds;
    float (*Bs)[68] = (float(*)[68])(lds + 32 * 33);
    const int tx = t & 15, ty = t >> 4;
    float acc[2][4] = {};
    const float* wbase = We + (size_t)e * 2048 * 1024 + (size_t)p * 1024 * 1024;
    for (int k0 = 0; k0 < 1024; k0 += 32) {
#pragma unroll
      for (int i = 0; i < 4; ++i) {
        int ix = t + i * 256;
        As[ix >> 5][ix & 31] =
            x1[(size_t)(chalf * 32 + (ix >> 5)) * 1024 + k0 + (ix & 31)];
      }
#pragma unroll
      for (int i = 0; i < 8; ++i) {
        int ix = t + i * 256;
        Bs[ix >> 6][ix & 63] = wbase[(size_t)(k0 + (ix >> 6)) * 1024 + n0 + (ix & 63)];
      }
      __syncthreads();
#pragma unroll
      for (int kk = 0; kk < 32; ++kk) {
        float av[2];
#pragma unroll
        for (int i = 0; i < 2; ++i) av[i] = As[ty * 2 + i][kk];
        f32x4v bv = *(const f32x4v*)&Bs[kk][tx * 4];
#pragma unroll
        for (int i = 0; i < 2; ++i)
#pragma unroll
          for (int j = 0; j < 4; ++j) acc[i][j] += av[i] * bv[j];
      }
      __syncthreads();
    }
#pragma unroll
    for (int i = 0; i < 2; ++i) {
      float* dst = pq + ((size_t)ep * 64 + chalf * 32 + ty * 2 + i) * 1024 + n0 + tx * 4;
#pragma unroll
      for (int j = 0; j < 4; ++j) dst[j] = acc[i][j];
    }
  }
}

// -------- build Y (bids 0..1023) + input-side reductions (1024..1032) -------
// extras: s1/c1b from w2ps/w2pc (8 blocks), gw3+scal (1 block). No atomics.
__global__ __launch_bounds__(256) void k_build_y(const float* __restrict__ pq,
                                                 const float* __restrict__ x2,
                                                 const float* __restrict__ be,
                                                 const int* __restrict__ cp,
                                                 const int* __restrict__ vis,
                                                 u16* __restrict__ Y,
                                                 const float* __restrict__ w2ps,
                                                 const float* __restrict__ w2pc,
                                                 const float* __restrict__ b2,
                                                 float* __restrict__ s1,
                                                 float* __restrict__ c1b,
                                                 const float* __restrict__ g2,
                                                 const float* __restrict__ bt2,
                                                 const float* __restrict__ W3,
                                                 float* __restrict__ gw3,
                                                 float* __restrict__ scal) {
  __shared__ float red[8];
  const int t = threadIdx.x;
  const int bidx = blockIdx.x;
  if (bidx < 1024) {
    for (int rr = 0; rr < 8; ++rr) {
      const int b = bidx * 8 + rr;
      const int e = vis[b];
      u16x8 o;
      if (t < 128) {
        const int c0 = cp[2 * b], c1 = cp[2 * b + 1];
        const size_t po = ((size_t)(e * 2) * 64 + c0) * 1024 + t * 8;
        const size_t qo = ((size_t)(e * 2 + 1) * 64 + c1) * 1024 + t * 8;
        const float* B = be + e * 1024 + t * 8;
#pragma unroll
        for (int i = 0; i < 8; ++i) {
          float v = pq[po + i] + pq[qo + i] + B[i];
          o[i] = f2bf(v > 0.f ? v : 0.f);
        }
        *(u16x8*)(Y + (size_t)b * 2048 + t * 8) = o;
      } else {
        const float* X = x2 + (size_t)b * 1024 + (size_t)(t - 128) * 8;
#pragma unroll
        for (int i = 0; i < 8; ++i) o[i] = f2bf(X[i]);
        *(u16x8*)(Y + (size_t)b * 2048 + 1024 + (size_t)(t - 128) * 8) = o;
      }
    }
  } else {
    const int r = bidx - 1024;
    if (r < 8) {
      const int nn = r * 256 + t;
      float s = 0.f, c = 0.f;
      for (int kb = 0; kb < 64; ++kb) {
        s += w2ps[(size_t)kb * 2048 + nn];
        c += w2pc[(size_t)kb * 2048 + nn];
      }
      s1[nn] = s;
      c1b[nn] = c + b2[nn];
    } else {
      float sg = 0.f, cb = 0.f;
      for (int i = 0; i < 8; ++i) {
        int c = i * 256 + t;
        float w3 = W3[c];
        float gv = g2[c] * w3;
        gw3[c] = gv;
        sg += gv;
        cb += bt2[c] * w3;
      }
#pragma unroll
      for (int off = 32; off > 0; off >>= 1) {
        sg += __shfl_down(sg, off, 64);
        cb += __shfl_down(cb, off, 64);
      }
      const int lane = t & 63, wv = t >> 6;
      if (lane == 0) { red[wv] = sg; red[4 + wv] = cb; }
      __syncthreads();
      if (t == 0) {
        scal[0] = red[0] + red[1] + red[2] + red[3];
        scal[1] = red[4] + red[5] + red[6] + red[7];
      }
    }
  }
}

// ============================================================================
// bf16 MFMA GEMM — 256x256 tile, BK=64, 8 waves (2Mx4N), 16x16x32 MFMA,
// XOR-chunk swizzle both-sides, XCD swizzle, setprio. Round-5 K-loop
// (intra-tile read pipelining, counted lgkm, 1 barrier/phase) UNCHANGED.
// MODE 0: C=relu(acc+bias) store; per-(row,cb) (sum,sumsq) -> sp_out.
// MODE 1: LN1 stats computed IN-BLOCK from sp (prologue, 2KB LDS table);
//         per-(row,cb) (S,SS,D) float4 -> part. No separate reduce kernel.
// ============================================================================
#define BARRIER __builtin_amdgcn_s_barrier()
#define WLG(n) asm volatile("s_waitcnt lgkmcnt(" #n ")" ::: "memory")
#define WVM(n) asm volatile("s_waitcnt vmcnt(" #n ")" ::: "memory")

template <int MODE>
__global__ __launch_bounds__(512, 2) void k_gemm(const u16* __restrict__ A,
                                                 const u16* __restrict__ BT,
                                                 const float* __restrict__ bias,
                                                 const float2* __restrict__ spin,
                                                 const float* __restrict__ s1,
                                                 const float* __restrict__ c1b,
                                                 const float* __restrict__ gw3,
                                                 float2* __restrict__ sp_out,
                                                 float4* __restrict__ part,
                                                 u16* __restrict__ C,
                                                 int M, int N, int K) {
  // [buf(2)][ab(2)][half(2)][128 rows][64 k] bf16 = 128 KiB
  __shared__ u16 smem[65536];
  __shared__ float2 stats_l[MODE ? 256 : 2];
  const int tid = threadIdx.x;
  const int lane = tid & 63;
  const int wave = tid >> 6;
  const int wm = wave >> 2;   // 0..1 -> 128 output rows
  const int wn = wave & 3;    // 0..3 -> 64 output cols

  // Bijective XCD swizzle.
  const int nx = gridDim.x, ny = gridDim.y;
  const int bid = blockIdx.y * nx + blockIdx.x;
  const int stripe = ny >> 3;                  // ny % 8 == 0 here
  const int xcd = bid & 7;
  const int loc = bid >> 3;
  const int by = xcd * stripe + (loc % stripe);
  const int bx = loc / stripe;
  const int tileM = by * 256;
  const int tileN = bx * 256;

  // ---- MODE 1 prologue: LN1 stats for rows [tileM, tileM+256) from sp.
  if (MODE == 1) {
    const int r2 = tid >> 1;      // 0..255
    const int h2 = tid & 1;       // 32-partial half
    const float2* p2 = spin + (size_t)(tileM + r2) * 64 + h2 * 32;
    float s = 0.f, ss = 0.f;
#pragma unroll
    for (int i = 0; i < 32; i += 2) {
      float4 v = *(const float4*)(p2 + i);
      s += v.x + v.z; ss += v.y + v.w;
    }
    s += __shfl_xor(s, 1); ss += __shfl_xor(ss, 1);
    if (h2 == 0) {
      float m = s * (1.f / 4096.f);
      float rs = rsqrtf(ss * (1.f / 4096.f) - m * m + 1e-5f);
      stats_l[r2] = make_float2(m, rs);
    }
    __syncthreads();
  }

  f32x4v acc[8][4];
#pragma unroll
  for (int i = 0; i < 8; ++i)
#pragma unroll
    for (int j = 0; j < 4; ++j) acc[i][j] = (f32x4v){0.f, 0.f, 0.f, 0.f};

  const int srow = tid >> 3;
  const int slc = ((tid & 7) ^ (srow & 7)) * 8;
  const u16* aG = A + (size_t)(tileM + srow) * K + slc;
  const u16* bG = BT + (size_t)(tileN + srow) * K + slc;

#define STAGE(ab, h, buf, kt)                                                  \
  do {                                                                         \
    u16* dst_ = smem + (buf) * 32768 + (ab) * 16384 + (h) * 8192 + tid * 8;    \
    const u16* g_ = ((ab) ? bG : aG) + (size_t)(h) * 128 * K + (size_t)(kt) * 64; \
    G2L16(g_, dst_);                                                           \
    G2L16(g_ + (size_t)64 * K, dst_ + 4096);                                   \
  } while (0)

  const int kp0 = (((lane >> 4) ^ (lane & 7)) * 8);
  const int kp1 = kp0 ^ 32;
  const int awoff = wm * 8192 + (lane & 15) * 64;
  const int bwoff = (wn >> 1) * 8192 + ((wn & 1) * 64 + (lane & 15)) * 64;

  bf16x8 af[2][4], ag[2][4], bfr[2][4];

#define RD_AF(buf)                                                             \
  do {                                                                         \
    const u16* ap_ = smem + (buf) * 32768 + awoff;                             \
    _Pragma("unroll") for (int q = 0; q < 4; ++q) {                            \
      af[0][q] = *(const bf16x8*)(ap_ + q * 1024 + kp0);                       \
      af[1][q] = *(const bf16x8*)(ap_ + q * 1024 + kp1);                       \
    }                                                                          \
  } while (0)

#define RD_AG(buf)                                                             \
  do {                                                                         \
    const u16* ap_ = smem + (buf) * 32768 + awoff + 4096;                      \
    _Pragma("unroll") for (int q = 0; q < 4; ++q) {                            \
      ag[0][q] = *(const bf16x8*)(ap_ + q * 1024 + kp0);                       \
      ag[1][q] = *(const bf16x8*)(ap_ + q * 1024 + kp1);                       \
    }                                                                          \
  } while (0)

#define RD_BB(buf)                                                             \
  do {                                                                         \
    const u16* bp_ = smem + (buf) * 32768 + 16384 + bwoff;                     \
    _Pragma("unroll") for (int j = 0; j < 4; ++j) {                            \
      bfr[0][j] = *(const bf16x8*)(bp_ + j * 1024 + kp0);                      \
      bfr[1][j] = *(const bf16x8*)(bp_ + j * 1024 + kp1);                      \
    }                                                                          \
  } while (0)

#define QUAD(AF, mh, nh)                                                       \
  do {                                                                         \
    __builtin_amdgcn_s_setprio(1);                                             \
    _Pragma("unroll") for (int kh = 0; kh < 2; ++kh)                           \
    _Pragma("unroll") for (int q = 0; q < 4; ++q)                              \
    _Pragma("unroll") for (int p = 0; p < 2; ++p)                              \
      acc[(mh) * 4 + q][(nh) * 2 + p] = __builtin_amdgcn_mfma_f32_16x16x32_bf16( \
          AF[kh][q], bfr[(kh)][(nh) * 2 + p], acc[(mh) * 4 + q][(nh) * 2 + p], 0, 0, 0); \
    __builtin_amdgcn_s_setprio(0);                                             \
  } while (0)

  const int nkt = K >> 6;       // 64-wide K-tiles
  const int niter = nkt >> 1;   // 2 K-tiles per iteration

  STAGE(1, 0, 0, 0);  // B0 T0
  STAGE(1, 1, 0, 0);  // B1 T0
  STAGE(0, 0, 0, 0);  // A0 T0
  STAGE(0, 1, 0, 0);  // A1 T0
  STAGE(1, 0, 1, 1);  // B0 T1
  STAGE(1, 1, 1, 1);  // B1 T1
  WVM(4);

  for (int it = 0; it < niter; ++it) {
    const int t1 = 2 * it + 1;
    int t2 = 2 * it + 2; if (t2 >= nkt) t2 = nkt - 1;
    int t3 = 2 * it + 3; if (t3 >= nkt) t3 = nkt - 1;
    // ===== tile T0 @ s0 =====
    BARRIER;
    RD_AF(0); RD_BB(0);
    STAGE(0, 0, 1, t1);
    WLG(4);
    QUAD(af, 0, 0);
    BARRIER;
    RD_AG(0);
    STAGE(0, 1, 1, t1);
    WLG(8);
    QUAD(af, 0, 1);
    BARRIER;
    STAGE(1, 0, 0, t2);
    WLG(0);
    QUAD(ag, 1, 0);
    BARRIER;
    STAGE(1, 1, 0, t2);
    QUAD(ag, 1, 1);
    WVM(4);
    // ===== tile T1 @ s1 =====
    BARRIER;
    RD_AF(1); RD_BB(1);
    STAGE(0, 0, 0, t2);
    WLG(4);
    QUAD(af, 0, 0);
    BARRIER;
    RD_AG(1);
    STAGE(0, 1, 0, t2);
    WLG(8);
    QUAD(af, 0, 1);
    BARRIER;
    STAGE(1, 0, 1, t3);
    WLG(0);
    QUAD(ag, 1, 0);
    BARRIER;
    STAGE(1, 1, 1, t3);
    QUAD(ag, 1, 1);
    WVM(4);
  }

  // ---- epilogue: C/D layout col = lane&15, row = (lane>>4)*4 + reg
  const int crow = tileM + wm * 128 + (lane >> 4) * 4;
  const int ccol = tileN + wn * 64 + (lane & 15);
  float cv0[4], cv1[4], cg[4];
#pragma unroll
  for (int ni = 0; ni < 4; ++ni) {
    const int c = ccol + ni * 16;
    if (MODE == 0) {
      cv0[ni] = bias[c];
    } else {
      cv0[ni] = s1[c];
      cv1[ni] = c1b[c];
      cg[ni] = gw3[c];
    }
  }
  const int cb = bx * 4 + wn;  // 64-col block index: [0,64) G1, [0,32) G2
#pragma unroll
  for (int mi = 0; mi < 8; ++mi) {
#pragma unroll
    for (int r = 0; r < 4; ++r) {
      const int row = crow + mi * 16 + r;
      if (MODE == 0) {
        float s_ = 0.f, ss_ = 0.f;
#pragma unroll
        for (int ni = 0; ni < 4; ++ni) {
          float v = acc[mi][ni][r] + cv0[ni];
          v = v > 0.f ? v : 0.f;
          s_ += v; ss_ += v * v;
          C[(size_t)row * N + ccol + ni * 16] = f2bf(v);
        }
#pragma unroll
        for (int off = 8; off >= 1; off >>= 1) {
          s_ += __shfl_xor(s_, off, 16);
          ss_ += __shfl_xor(ss_, off, 16);
        }
        if ((lane & 15) == 0)
          sp_out[(size_t)row * 64 + cb] = make_float2(s_, ss_);
      } else {
        float2 st = stats_l[row - tileM];
        const float m = st.x, rs = st.y;
        float s_ = 0.f, ss_ = 0.f, d_ = 0.f;
#pragma unroll
        for (int ni = 0; ni < 4; ++ni) {
          float v = rs * acc[mi][ni][r] - rs * m * cv0[ni] + cv1[ni];
          v = v > 0.f ? v : 0.f;
          s_ += v; ss_ += v * v; d_ += v * cg[ni];
        }
#pragma unroll
        for (int off = 8; off >= 1; off >>= 1) {
          s_ += __shfl_xor(s_, off, 16);
          ss_ += __shfl_xor(ss_, off, 16);
          d_ += __shfl_xor(d_, off, 16);
        }
        if ((lane & 15) == 0)
          part[(size_t)row * 32 + cb] = make_float4(s_, ss_, d_, 0.f);
      }
    }
  }
}

// ------- final: out[row] = sigmoid(rs*D - rs*m*SG + CB + b3) ----------------
__global__ __launch_bounds__(256) void k_final(const float4* __restrict__ part,
                                               const float* __restrict__ scal,
                                               const float* __restrict__ b3,
                                               float* __restrict__ out) {
  const int t = threadIdx.x;
  const int g = t >> 4, l = t & 15;
  const int row = blockIdx.x * 16 + g;
  float4 a = part[(size_t)row * 32 + l * 2];
  float4 b = part[(size_t)row * 32 + l * 2 + 1];
  float S = a.x + b.x, SS = a.y + b.y, D = a.z + b.z;
#pragma unroll
  for (int off = 8; off >= 1; off >>= 1) {
    S += __shfl_xor(S, off, 16);
    SS += __shfl_xor(SS, off, 16);
    D += __shfl_xor(D, off, 16);
  }
  if (l == 0) {
    float m = S * (1.f / 2048.f);
    float rs = rsqrtf(SS * (1.f / 2048.f) - m * m + 1e-5f);
    float logit = rs * D - rs * m * scal[0] + scal[1] + b3[0];
    out[row] = 1.f / (1.f + expf(-logit));
  }
}

extern "C" void kernel_launch(void* const* d_in, const int* in_sizes, int n_in,
                              void* d_out, int out_size, void* d_ws, size_t ws_size,
                              hipStream_t stream) {
  const float* x1 = (const float*)d_in[0];
  const float* x2 = (const float*)d_in[1];
  const float* We = (const float*)d_in[2];
  const float* be = (const float*)d_in[3];
  const float* W1 = (const float*)d_in[4];
  const float* b1 = (const float*)d_in[5];
  const float* g1 = (const float*)d_in[6];
  const float* bt1 = (const float*)d_in[7];
  const float* W2 = (const float*)d_in[8];
  const float* b2 = (const float*)d_in[9];
  const float* g2 = (const float*)d_in[10];
  const float* bt2 = (const float*)d_in[11];
  const float* W3 = (const float*)d_in[12];
  const float* b3 = (const float*)d_in[13];
  const int* cp = (const int*)d_in[14];
  const int* vis = (const int*)d_in[15];
  float* out = (float*)d_out;

  char* ws = (char*)d_ws;
  u16* W1T  = (u16*)(ws);                  // 4096x2048 bf16 = 16 MiB
  u16* W2gT = (u16*)(ws + 16777216);       // 2048x4096 bf16 = 16 MiB
  u16* Y    = (u16*)(ws + 33554432);       // 8192x2048 bf16 = 32 MiB
  u16* H1   = (u16*)(ws + 67108864);       // 8192x4096 bf16 = 64 MiB
  float* PQ = (float*)(ws + 134217728);    // 8x64x1024 f32 = 2 MiB
  // sp (LN1 partials, 8192x64 float2 = 4 MiB) reuses PQ region (dead after
  // build_y). part (8192x32 float4 = 4 MiB) lives in the dead Y region
  // (Y consumed by GEMM1; GEMM2 writes part there; k_final reads it).
  float2* sp = (float2*)(ws + 134217728);
  float4* part = (float4*)(ws + 33554432);
  float* s1   = (float*)(ws + 138477568);     // 8 KiB
  float* c1b  = (float*)(ws + 138485760);     // 8 KiB
  float* w2ps = (float*)(ws + 138493952);     // 64x2048 f32 = 512 KiB
  float* w2pc = (float*)(ws + 139018240);     // 512 KiB
  float* gw3  = (float*)(ws + 139542528);     // 8 KiB
  float* scal = (float*)(ws + 139550720);     // 2 f32

  k_prep<<<4352, 256, 0, stream>>>(W1, W1T, W2, W2gT, g1, bt1, w2ps, w2pc,
                                   x1, We, PQ);
  k_build_y<<<1033, 256, 0, stream>>>(PQ, x2, be, cp, vis, Y,
                                      w2ps, w2pc, b2, s1, c1b,
                                      g2, bt2, W3, gw3, scal);
  k_gemm<0><<<dim3(16, 32), 512, 0, stream>>>(
      Y, W1T, b1, nullptr, nullptr, nullptr, nullptr, sp, nullptr, H1,
      8192, 4096, 2048);
  k_gemm<1><<<dim3(8, 32), 512, 0, stream>>>(
      H1, W2gT, nullptr, sp, s1, c1b, gw3, nullptr, part, nullptr,
      8192, 2048, 4096);
  k_final<<<512, 256, 0, stream>>>(part, scal, b3, out);
}